// Round 1
// baseline (392.292 us; speedup 1.0000x reference)
//
#include <hip/hip_runtime.h>

// ConvLSTM2D: B=16,T=8,H=W=256,C=3,F=64,stride=16 -> Ho=Wo=16, 4F=256
#define NB   16
#define NT   8
#define HIN  256
#define CIN  3
#define NF   64
#define OC   256   // 4*F
#define HO   16
#define WOUT 16

// ---------------- Kernel 1: strided input conv (all B*T at once) -------------
// grid (HO, B*T), block 256 (thread = oc). SAME pad == 0 for this shape.
__global__ __launch_bounds__(256) void input_conv(
    const float* __restrict__ x, const float* __restrict__ Wx,
    const float* __restrict__ bias, float* __restrict__ xc)
{
  const int ho = blockIdx.x;
  const int bt = blockIdx.y;
  const int oc = threadIdx.x;

  // patch[r][wo][k], r=3 rows, 16 wo, k = kw*3+c (9)
  __shared__ float patch[432];
  for (int idx = threadIdx.x; idx < 432; idx += 256) {
    int r = idx / 144, rem = idx % 144;
    int wo = rem / 9, k = rem % 9;
    int kw = k / 3, c = k % 3;
    patch[idx] = x[(((size_t)bt * HIN + (ho * 16 + r)) * HIN + (wo * 16 + kw)) * CIN + c];
  }
  float w[27];
#pragma unroll
  for (int k = 0; k < 27; ++k) w[k] = Wx[(size_t)k * OC + oc];
  __syncthreads();

  const float bv = bias[oc];
  for (int wo = 0; wo < 16; ++wo) {
    float acc = bv;
#pragma unroll
    for (int kh = 0; kh < 3; ++kh)
#pragma unroll
      for (int k9 = 0; k9 < 9; ++k9)
        acc = fmaf(patch[(kh * 16 + wo) * 9 + k9], w[kh * 9 + k9], acc);
    xc[(((size_t)bt * HO + ho) * WOUT + wo) * OC + oc] = acc;
  }
}

// ---------------- Kernel 2: one LSTM step -----------------------------------
// grid (HO, B), block 512: tid = half*256 + oc ; half covers wo in [half*8, half*8+8)
// z = xc[t] + conv3x3(h_in, Wh); gates; c,h update. first==1 -> h_in/c not read.
__global__ __launch_bounds__(512) void lstm_step(
    const float* __restrict__ xc, const float* __restrict__ Wh,
    const float* __restrict__ h_in, float* __restrict__ c_st,
    float* __restrict__ h_out, int t, int first)
{
  const int ho   = blockIdx.x;
  const int b    = blockIdx.y;
  const int tid  = threadIdx.x;
  const int oc   = tid & 255;
  const int half = tid >> 8;
  const int wbase = half * 8;

  __shared__ float patch[3 * 18 * 64];  // h rows ho-1..ho+1, cols -1..16, 64 ch
  __shared__ float zbuf[WOUT * OC];     // 16 KB

  float acc[8];
#pragma unroll
  for (int w = 0; w < 8; ++w)
    acc[w] = xc[((((size_t)b * NT + t) * HO + ho) * WOUT + (wbase + w)) * OC + oc];

  if (!first) {
    // stage h patch (zero-padded halo) as float4s
    for (int j = tid; j < 864; j += 512) {
      int ci4 = j & 15;
      int rest = j >> 4;          // 0..53
      int p = rest % 18, r = rest / 18;
      int y = ho - 1 + r, xx = p - 1;
      float4 v = make_float4(0.f, 0.f, 0.f, 0.f);
      if ((unsigned)y < 16u && (unsigned)xx < 16u)
        v = *(const float4*)&h_in[(((size_t)b * 16 + y) * 16 + xx) * NF + ci4 * 4];
      *(float4*)&patch[(r * 18 + p) * 64 + ci4 * 4] = v;
    }
    __syncthreads();

    for (int kh = 0; kh < 3; ++kh) {
#pragma unroll 2
      for (int cg = 0; cg < 16; ++cg) {
        float wv[12];
#pragma unroll
        for (int kw = 0; kw < 3; ++kw)
#pragma unroll
          for (int c = 0; c < 4; ++c)
            wv[kw * 4 + c] = Wh[(((size_t)(kh * 3 + kw) * 64) + cg * 4 + c) * OC + oc];
#pragma unroll
        for (int col = 0; col < 10; ++col) {
          float4 h4 = *(const float4*)&patch[(kh * 18 + wbase + col) * 64 + cg * 4];
#pragma unroll
          for (int kw = 0; kw < 3; ++kw) {
            int w = col - kw;
            if (w >= 0 && w < 8) {
              acc[w] = fmaf(h4.x, wv[kw * 4 + 0], acc[w]);
              acc[w] = fmaf(h4.y, wv[kw * 4 + 1], acc[w]);
              acc[w] = fmaf(h4.z, wv[kw * 4 + 2], acc[w]);
              acc[w] = fmaf(h4.w, wv[kw * 4 + 3], acc[w]);
            }
          }
        }
      }
    }
  }

  // exchange z across oc for gate mixing
#pragma unroll
  for (int w = 0; w < 8; ++w)
    zbuf[(wbase + w) * OC + oc] = acc[w];
  __syncthreads();

#pragma unroll
  for (int rep = 0; rep < 2; ++rep) {
    int item = tid + rep * 512;  // 0..1023
    int wo = item >> 6;
    int f  = item & 63;
    float zi = zbuf[wo * OC + f];
    float zf = zbuf[wo * OC + 64 + f];
    float zg = zbuf[wo * OC + 128 + f];
    float zo = zbuf[wo * OC + 192 + f];
    float ig = fminf(fmaxf(fmaf(zi, 0.2f, 0.5f), 0.f), 1.f);
    float fg = fminf(fmaxf(fmaf(zf, 0.2f, 0.5f), 0.f), 1.f);
    float og = fminf(fmaxf(fmaf(zo, 0.2f, 0.5f), 0.f), 1.f);
    size_t cidx = (((size_t)b * 16 + ho) * 16 + wo) * NF + f;
    float cold = first ? 0.f : c_st[cidx];
    float cnew = fmaf(fg, cold, ig * zg);
    c_st[cidx] = cnew;
    h_out[cidx] = og * cnew;
  }
}

extern "C" void kernel_launch(void* const* d_in, const int* in_sizes, int n_in,
                              void* d_out, int out_size, void* d_ws, size_t ws_size,
                              hipStream_t stream) {
  const float* x    = (const float*)d_in[0];
  const float* Wx   = (const float*)d_in[1];
  const float* Wh   = (const float*)d_in[2];
  const float* bias = (const float*)d_in[3];
  float* out = (float*)d_out;

  float* ws   = (float*)d_ws;
  float* xc   = ws;                                    // 8,388,608 floats
  float* h0   = xc + (size_t)NB * NT * HO * WOUT * OC; // 262,144 floats
  float* h1   = h0 + (size_t)NB * HO * WOUT * NF;
  float* cbuf = h1 + (size_t)NB * HO * WOUT * NF;

  input_conv<<<dim3(HO, NB * NT), 256, 0, stream>>>(x, Wx, bias, xc);

  for (int t = 0; t < NT; ++t) {
    const float* hin = (t & 1) ? h0 : h1;              // unused at t==0
    float* hout = (t == NT - 1) ? out : ((t & 1) ? h1 : h0);
    lstm_step<<<dim3(HO, NB), 512, 0, stream>>>(xc, Wh, hin, cbuf, hout, t, t == 0);
  }
}

// Round 2
// 267.327 us; speedup vs baseline: 1.4675x; 1.4675x over previous
//
#include <hip/hip_runtime.h>

// ConvLSTM2D: B=16,T=8,H=W=256,C=3,F=64,stride=16 -> Ho=Wo=16, 4F=256
#define NB   16
#define NT   8
#define HIN  256
#define CIN  3
#define NF   64
#define OC   256
#define HO   16
#define WOUT 16

typedef short short8 __attribute__((ext_vector_type(8)));
typedef float f32x4 __attribute__((ext_vector_type(4)));

__device__ __forceinline__ unsigned short f2bf(float x) {
  union { float f; unsigned int u; } v; v.f = x;
  unsigned int r = v.u + 0x7fffu + ((v.u >> 16) & 1u);
  return (unsigned short)(r >> 16);
}
__device__ __forceinline__ float bf2f(unsigned short b) {
  union { unsigned int u; float f; } v; v.u = ((unsigned int)b) << 16;
  return v.f;
}

// ---------------- Kernel 1: strided input conv, permuted-column output -------
// grid (HO, B*T), block 256 (thread = oc). SAME pad == 0 for this shape.
// Output column permuted: n = (oc&63)*4 + (oc>>6)  (filter-major, gate-minor)
__global__ __launch_bounds__(256) void input_conv(
    const float* __restrict__ x, const float* __restrict__ Wx,
    const float* __restrict__ bias, float* __restrict__ xc)
{
  const int ho = blockIdx.x;
  const int bt = blockIdx.y;
  const int oc = threadIdx.x;

  __shared__ float patch[432];  // [r(3)][wo(16)][k(9)]
  for (int idx = threadIdx.x; idx < 432; idx += 256) {
    int r = idx / 144, rem = idx % 144;
    int wo = rem / 9, k = rem % 9;
    int kw = k / 3, c = k % 3;
    patch[idx] = x[(((size_t)bt * HIN + (ho * 16 + r)) * HIN + (wo * 16 + kw)) * CIN + c];
  }
  float w[27];
#pragma unroll
  for (int k = 0; k < 27; ++k) w[k] = Wx[(size_t)k * OC + oc];
  __syncthreads();

  const float bv = bias[oc];
  const int n = (oc & 63) * 4 + (oc >> 6);
  for (int wo = 0; wo < 16; ++wo) {
    float acc = bv;
#pragma unroll
    for (int kh = 0; kh < 3; ++kh)
#pragma unroll
      for (int k9 = 0; k9 < 9; ++k9)
        acc = fmaf(patch[(kh * 16 + wo) * 9 + k9], w[kh * 9 + k9], acc);
    xc[(((size_t)bt * HO + ho) * WOUT + wo) * OC + n] = acc;
  }
}

// ---------------- Kernel 2: Wh -> split-bf16 panels Bp[27][256][64] ----------
// chunk c = pass*9 + (kh*3+kw); pass0: hi (A=hi), pass1: lo (A=hi), pass2: hi (A=lo)
// n is permuted column, k = ci.
__global__ __launch_bounds__(256) void conv_weights(
    const float* __restrict__ Wh, unsigned short* __restrict__ Bp)
{
  int idx = blockIdx.x * 256 + threadIdx.x;   // < 27*256*64 = 442368
  int c   = idx >> 14;
  int rem = idx & 16383;
  int n   = rem >> 6;
  int k   = rem & 63;
  int pass = c / 9, tap = c % 9;
  int kh = tap / 3, kw = tap % 3;
  int oc = (n & 3) * 64 + (n >> 2);           // inverse permutation
  float w = Wh[(size_t)((kh * 3 + kw) * 64 + k) * OC + oc];
  unsigned short hi = f2bf(w);
  Bp[idx] = (pass == 1) ? f2bf(w - bf2f(hi)) : hi;
}

// ---------------- Kernel 3: one LSTM step via split-bf16 MFMA GEMM -----------
// GEMM: M=4096 (b,ho,wo), N=256 (permuted gates), K''=1728 (3 passes x 9 taps x 64ci)
// grid (64, 4): mb -> b=mb>>2, ho0=(mb&3)*4 ; nb -> n0=nb*64. block 256 = 4 waves,
// wave tile 32x32 (2x2 16x16x32 frags). K chunked at 64 (one tap), double-buffered.
__global__ __launch_bounds__(256) void lstm_step_mfma(
    const float* __restrict__ xc, const unsigned short* __restrict__ Bp,
    const unsigned short* __restrict__ h_hi_in, const unsigned short* __restrict__ h_lo_in,
    unsigned short* __restrict__ h_hi_out, unsigned short* __restrict__ h_lo_out,
    float* __restrict__ c_st, float* __restrict__ out,
    int t, int first, int last)
{
  const int mb  = blockIdx.x;
  const int nb  = blockIdx.y;
  const int b   = mb >> 2;
  const int ho0 = (mb & 3) * 4;
  const int n0  = nb * 64;
  const int tid = threadIdx.x;

  // A/B tiles: [buf][A=0/B=1][row 64][k 64 + pad 8] bf16, stride 144 B (bank-friendly)
  __shared__ __align__(16) union SM {
    unsigned short ab[2][2][64][72];  // 36864 B
    float z[64][80];                  // 20480 B (epilogue overlay)
  } sm;

  f32x4 acc[2][2];
#pragma unroll
  for (int i = 0; i < 2; ++i)
#pragma unroll
    for (int j = 0; j < 2; ++j) acc[i][j] = (f32x4)(0.0f);

  const int row = tid >> 2;   // 0..63 (A: m-row / B: n-row)
  const int q   = tid & 3;    // 16-elem quarter of k

  float4 ra0, ra1, rb0, rb1;
  const float4 zero4 = make_float4(0.f, 0.f, 0.f, 0.f);

  auto load_chunk = [&](int c) {
    int pass = c / 9, tap = c % 9;
    int kh = tap / 3, kw = tap % 3;
    const unsigned short* hsrc = (pass < 2) ? h_hi_in : h_lo_in;
    int y = ho0 + (row >> 4) + kh - 1;
    int xx = (row & 15) + kw - 1;
    ra0 = zero4; ra1 = zero4;
    if ((unsigned)y < 16u && (unsigned)xx < 16u) {
      const float4* p = (const float4*)(hsrc + (((size_t)b * 256 + y * 16 + xx) * 64 + q * 16));
      ra0 = p[0]; ra1 = p[1];
    }
    const float4* pb = (const float4*)(Bp + (((size_t)c * 256 + n0 + row) * 64 + q * 16));
    rb0 = pb[0]; rb1 = pb[1];
  };
  auto write_chunk = [&](int buf) {
    *(float4*)&sm.ab[buf][0][row][q * 16]     = ra0;
    *(float4*)&sm.ab[buf][0][row][q * 16 + 8] = ra1;
    *(float4*)&sm.ab[buf][1][row][q * 16]     = rb0;
    *(float4*)&sm.ab[buf][1][row][q * 16 + 8] = rb1;
  };

  const int wv   = tid >> 6;
  const int lane = tid & 63;
  const int moff = (wv & 1) * 32;
  const int noff = (wv >> 1) * 32;
  const int r16  = lane & 15;
  const int kg   = lane >> 4;

  auto compute_chunk = [&](int buf) {
#pragma unroll
    for (int kh2 = 0; kh2 < 2; ++kh2) {
      int ko = kh2 * 32 + kg * 8;
      short8 a0 = *(const short8*)&sm.ab[buf][0][moff + r16][ko];
      short8 a1 = *(const short8*)&sm.ab[buf][0][moff + 16 + r16][ko];
      short8 b0 = *(const short8*)&sm.ab[buf][1][noff + r16][ko];
      short8 b1 = *(const short8*)&sm.ab[buf][1][noff + 16 + r16][ko];
      acc[0][0] = __builtin_amdgcn_mfma_f32_16x16x32_bf16(a0, b0, acc[0][0], 0, 0, 0);
      acc[0][1] = __builtin_amdgcn_mfma_f32_16x16x32_bf16(a0, b1, acc[0][1], 0, 0, 0);
      acc[1][0] = __builtin_amdgcn_mfma_f32_16x16x32_bf16(a1, b0, acc[1][0], 0, 0, 0);
      acc[1][1] = __builtin_amdgcn_mfma_f32_16x16x32_bf16(a1, b1, acc[1][1], 0, 0, 0);
    }
  };

  if (!first) {
    load_chunk(0);
    for (int c = 0; c < 27; ++c) {
      write_chunk(c & 1);
      __syncthreads();
      if (c < 26) load_chunk(c + 1);   // issue next loads; latency hides under MFMA
      compute_chunk(c & 1);
    }
  }
  __syncthreads();

  // dump conv result into z overlay (zeros when first)
#pragma unroll
  for (int mi = 0; mi < 2; ++mi)
#pragma unroll
    for (int ni = 0; ni < 2; ++ni)
#pragma unroll
      for (int i = 0; i < 4; ++i)
        sm.z[moff + mi * 16 + kg * 4 + i][noff + ni * 16 + r16] = acc[mi][ni][i];
  __syncthreads();

  // fused cell update: z = conv + xc ; gates ; c,h
  const int fl   = tid & 15;            // filter within block's 16
  const int mgrp = (tid >> 4) * 4;
  const int fglob = nb * 16 + fl;
  const float* xcb = xc + ((size_t)(b * NT + t) * 256) * 256;
#pragma unroll
  for (int mi = 0; mi < 4; ++mi) {
    int m   = mgrp + mi;
    int pos = ho0 * 16 + m;             // ho*16+wo
    float4 zq = *(const float4*)&sm.z[m][fl * 4];
    float4 xq = *(const float4*)&xcb[(size_t)pos * OC + n0 + fl * 4];
    float zi = zq.x + xq.x, zf = zq.y + xq.y, zg = zq.z + xq.z, zo = zq.w + xq.w;
    float ig = fminf(fmaxf(fmaf(zi, 0.2f, 0.5f), 0.f), 1.f);
    float fg = fminf(fmaxf(fmaf(zf, 0.2f, 0.5f), 0.f), 1.f);
    float og = fminf(fmaxf(fmaf(zo, 0.2f, 0.5f), 0.f), 1.f);
    size_t cidx = ((size_t)b * 256 + pos) * NF + fglob;
    float cold = first ? 0.f : c_st[cidx];
    float cnew = fmaf(fg, cold, ig * zg);
    c_st[cidx] = cnew;
    float h = og * cnew;
    unsigned short hh = f2bf(h);
    h_hi_out[cidx] = hh;
    h_lo_out[cidx] = f2bf(h - bf2f(hh));
    if (last) out[cidx] = h;
  }
}

extern "C" void kernel_launch(void* const* d_in, const int* in_sizes, int n_in,
                              void* d_out, int out_size, void* d_ws, size_t ws_size,
                              hipStream_t stream) {
  const float* x    = (const float*)d_in[0];
  const float* Wx   = (const float*)d_in[1];
  const float* Wh   = (const float*)d_in[2];
  const float* bias = (const float*)d_in[3];
  float* out = (float*)d_out;

  char* ws = (char*)d_ws;
  float*          xc  = (float*)ws;                          // 33,554,432 B
  unsigned short* Bp  = (unsigned short*)(ws + 33554432);    //    884,736 B
  unsigned short* h_hi[2] = { (unsigned short*)(ws + 34439168),
                              (unsigned short*)(ws + 34963456) };
  unsigned short* h_lo[2] = { (unsigned short*)(ws + 35487744),
                              (unsigned short*)(ws + 36012032) };
  float*          cbuf = (float*)(ws + 36536320);            // 1,048,576 B

  input_conv<<<dim3(HO, NB * NT), 256, 0, stream>>>(x, Wx, bias, xc);
  conv_weights<<<1728, 256, 0, stream>>>(Wh, Bp);

  for (int t = 0; t < NT; ++t) {
    int in  = t & 1;
    int outb = (t + 1) & 1;
    lstm_step_mfma<<<dim3(64, 4), 256, 0, stream>>>(
        xc, Bp, h_hi[in], h_lo[in], h_hi[outb], h_lo[outb],
        cbuf, out, t, t == 0, t == NT - 1);
  }
}

// Round 3
// 218.611 us; speedup vs baseline: 1.7945x; 1.2228x over previous
//
#include <hip/hip_runtime.h>

// ConvLSTM2D: B=16,T=8,H=W=256,C=3,F=64,stride=16 -> Ho=Wo=16, 4F=256
#define NB   16
#define NT   8
#define HIN  256
#define CIN  3
#define NF   64
#define OC   256
#define HO   16
#define WOUT 16

typedef short short8 __attribute__((ext_vector_type(8)));
typedef float f32x4  __attribute__((ext_vector_type(4)));
typedef float f32x16 __attribute__((ext_vector_type(16)));

__device__ __forceinline__ unsigned short f2bf(float x) {
  union { float f; unsigned int u; } v; v.f = x;
  unsigned int r = v.u + 0x7fffu + ((v.u >> 16) & 1u);
  return (unsigned short)(r >> 16);
}
__device__ __forceinline__ float bf2f(unsigned short b) {
  union { unsigned int u; float f; } v; v.u = ((unsigned int)b) << 16;
  return v.f;
}

// ---------------- Kernel 1: strided input conv, permuted-column output -------
// n = (oc&63)*4 + (oc>>6)  (filter-major, gate-minor); bias folded in.
__global__ __launch_bounds__(256) void input_conv(
    const float* __restrict__ x, const float* __restrict__ Wx,
    const float* __restrict__ bias, float* __restrict__ xc)
{
  const int ho = blockIdx.x;
  const int bt = blockIdx.y;
  const int oc = threadIdx.x;

  __shared__ float patch[432];  // [r(3)][wo(16)][k(9)]
  for (int idx = threadIdx.x; idx < 432; idx += 256) {
    int r = idx / 144, rem = idx % 144;
    int wo = rem / 9, k = rem % 9;
    int kw = k / 3, c = k % 3;
    patch[idx] = x[(((size_t)bt * HIN + (ho * 16 + r)) * HIN + (wo * 16 + kw)) * CIN + c];
  }
  float w[27];
#pragma unroll
  for (int k = 0; k < 27; ++k) w[k] = Wx[(size_t)k * OC + oc];
  __syncthreads();

  const float bv = bias[oc];
  const int n = (oc & 63) * 4 + (oc >> 6);
  for (int wo = 0; wo < 16; ++wo) {
    float acc = bv;
#pragma unroll
    for (int kh = 0; kh < 3; ++kh)
#pragma unroll
      for (int k9 = 0; k9 < 9; ++k9)
        acc = fmaf(patch[(kh * 16 + wo) * 9 + k9], w[kh * 9 + k9], acc);
    xc[(((size_t)bt * HO + ho) * WOUT + wo) * OC + n] = acc;
  }
}

// ---------------- Kernel 2: Wh -> fragment-contiguous split-bf16 panels ------
// Bp2[c(27)][nfg(8)][q(4)][lane(64)][j(8)]: chunk c = pass*9+tap;
// lane: n = nfg*32+(lane&31), ci = q*16+(lane>>5)*8+j. pass0/2: hi|lo of B? ->
// pass0: B=hi, pass1: B=lo (A=hi), pass2: B=hi (A=lo).
__global__ __launch_bounds__(256) void conv_weights(
    const float* __restrict__ Wh, unsigned short* __restrict__ Bp2)
{
  int thr = blockIdx.x * 256 + threadIdx.x;   // grid 216*256 = 55296 exact
  int lane = thr & 63;
  int q    = (thr >> 6) & 3;
  int nfg  = (thr >> 8) & 7;
  int c    = thr >> 11;                       // 0..26
  int pass = (c >= 18) ? 2 : (c >= 9 ? 1 : 0);
  int tap  = c - pass * 9;
  int n    = nfg * 32 + (lane & 31);
  int kb   = q * 16 + (lane >> 5) * 8;
  int oc   = (n & 3) * 64 + (n >> 2);         // inverse column permutation
  short8 v;
#pragma unroll
  for (int j = 0; j < 8; ++j) {
    float w = Wh[(size_t)(tap * 64 + kb + j) * OC + oc];
    unsigned short hi = f2bf(w);
    v[j] = (short)((pass == 1) ? f2bf(w - bf2f(hi)) : hi);
  }
  *(short8*)(Bp2 + (size_t)thr * 8) = v;
}

// ---------------- Kernel 3: LSTM step, LDS-free MFMA, in-block split-K -------
// GEMM M=4096,N=256,K''=1728. Block: 32(m)x64(n) tile, 8 waves split-K over
// 108 k-units (27 chunks x 4 kq). Wave frags 32x32x16 bf16, straight from L2.
// h kept in fragment layout h2[b][kq(8)][pos(256)][8] (hi & lo planes).
__global__ __launch_bounds__(512, 4) void lstm_step_mfma(
    const float* __restrict__ xc, const unsigned short* __restrict__ Bp2,
    const unsigned short* __restrict__ h_hi_in, const unsigned short* __restrict__ h_lo_in,
    unsigned short* __restrict__ h_hi_out, unsigned short* __restrict__ h_lo_out,
    float* __restrict__ c_st, float* __restrict__ out,
    int t, int first, int last)
{
  const int mb   = blockIdx.x;           // 0..127
  const int nb   = blockIdx.y;           // 0..3
  const int b    = mb >> 3;
  const int pos0 = (mb & 7) * 32;        // 32 spatial positions (2 ho rows)
  const int tid  = threadIdx.x;
  const int w    = tid >> 6;             // wave 0..7 (split-K group)
  const int lane = tid & 63;
  const int col  = lane & 31;            // m (A) / n (B) / col (C)
  const int kh2  = lane >> 5;            // k half-group

  __shared__ float zpart[8][32][64];     // 64 KB partials

  if (!first) {
    f32x16 acc0 = (f32x16)(0.0f), acc1 = (f32x16)(0.0f);

    const int pos = pos0 + col;
    const int hoq = pos >> 4, woq = pos & 15;

    auto unit_load = [&](int u, short8& a, short8& b0, short8& b1) {
      int c = u >> 2, q = u & 3;
      int pass = (c >= 18) ? 2 : (c >= 9 ? 1 : 0);
      int tap  = c - pass * 9;
      int kh = ((tap * 11) >> 5) - 1;        // tap/3 - 1
      int kw = (tap - (kh + 1) * 3) - 1;     // tap%3 - 1
      int y = hoq + kh, xx = woq + kw;
      a = (short8)0;
      if ((unsigned)y < 16u && (unsigned)xx < 16u) {
        const unsigned short* hsrc = (pass < 2) ? h_hi_in : h_lo_in;
        int kq = q * 2 + kh2;
        a = *(const short8*)(hsrc + ((((b * 8 + kq) * 256) + (y * 16 + xx)) * 8));
      }
      const unsigned short* bp = Bp2 + (size_t)((((c * 8 + nb * 2) * 4 + q) * 64 + lane) * 8);
      b0 = *(const short8*)bp;
      b1 = *(const short8*)(bp + 2048);      // next n-frag: 4*64*8
    };

    short8 a, b0, b1, a2, b02, b12;
    int u = w;
    unit_load(u, a, b0, b1);
    for (; u + 8 < 108; u += 8) {
      unit_load(u + 8, a2, b02, b12);        // prefetch next unit
      acc0 = __builtin_amdgcn_mfma_f32_32x32x16_bf16(a, b0, acc0, 0, 0, 0);
      acc1 = __builtin_amdgcn_mfma_f32_32x32x16_bf16(a, b1, acc1, 0, 0, 0);
      a = a2; b0 = b02; b1 = b12;
    }
    acc0 = __builtin_amdgcn_mfma_f32_32x32x16_bf16(a, b0, acc0, 0, 0, 0);
    acc1 = __builtin_amdgcn_mfma_f32_32x32x16_bf16(a, b1, acc1, 0, 0, 0);

    // C layout (verified m74/m101): col = lane&31, row = (r&3)+8*(r>>2)+4*(lane>>5)
#pragma unroll
    for (int r = 0; r < 16; ++r) {
      int row = (r & 3) + 8 * (r >> 2) + 4 * kh2;
      zpart[w][row][col]      = acc0[r];
      zpart[w][row][32 + col] = acc1[r];
    }
  }
  __syncthreads();

  // fused reduce + cell update: thread = (m 0..31, fl 0..15)
  const int m  = tid >> 4;
  const int fl = tid & 15;
  const int pos = pos0 + m;
  float4 z = make_float4(0.f, 0.f, 0.f, 0.f);
  if (!first) {
#pragma unroll
    for (int ww = 0; ww < 8; ++ww) {
      float4 p = *(const float4*)&zpart[ww][m][fl * 4];
      z.x += p.x; z.y += p.y; z.z += p.z; z.w += p.w;
    }
  }
  const float4 xq = *(const float4*)&xc[(((size_t)(b * NT + t) * 256) + pos) * OC + nb * 64 + fl * 4];
  float zi = z.x + xq.x, zf = z.y + xq.y, zg = z.z + xq.z, zo = z.w + xq.w;
  float ig = fminf(fmaxf(fmaf(zi, 0.2f, 0.5f), 0.f), 1.f);
  float fg = fminf(fmaxf(fmaf(zf, 0.2f, 0.5f), 0.f), 1.f);
  float og = fminf(fmaxf(fmaf(zo, 0.2f, 0.5f), 0.f), 1.f);
  const int f = nb * 16 + fl;
  size_t cidx = ((size_t)b * 256 + pos) * NF + f;
  float cold = first ? 0.f : c_st[cidx];
  float cnew = fmaf(fg, cold, ig * zg);
  c_st[cidx] = cnew;
  float h = og * cnew;
  unsigned short hh = f2bf(h);
  size_t hidx = ((size_t)(b * 8 + (f >> 3)) * 256 + pos) * 8 + (f & 7);
  h_hi_out[hidx] = hh;
  h_lo_out[hidx] = f2bf(h - bf2f(hh));
  if (last) out[cidx] = h;
}

extern "C" void kernel_launch(void* const* d_in, const int* in_sizes, int n_in,
                              void* d_out, int out_size, void* d_ws, size_t ws_size,
                              hipStream_t stream) {
  const float* x    = (const float*)d_in[0];
  const float* Wx   = (const float*)d_in[1];
  const float* Wh   = (const float*)d_in[2];
  const float* bias = (const float*)d_in[3];
  float* out = (float*)d_out;

  char* ws = (char*)d_ws;
  float*          xc  = (float*)ws;                          // 33,554,432 B
  unsigned short* Bp2 = (unsigned short*)(ws + 33554432);    //    884,736 B
  unsigned short* h_hi[2] = { (unsigned short*)(ws + 34439168),
                              (unsigned short*)(ws + 34963456) };
  unsigned short* h_lo[2] = { (unsigned short*)(ws + 35487744),
                              (unsigned short*)(ws + 36012032) };
  float*          cbuf = (float*)(ws + 36536320);            // 4,194,304 B

  input_conv<<<dim3(HO, NB * NT), 256, 0, stream>>>(x, Wx, bias, xc);
  conv_weights<<<216, 256, 0, stream>>>(Wh, Bp2);

  for (int t = 0; t < NT; ++t) {
    int in  = t & 1;
    int ob  = (t + 1) & 1;
    lstm_step_mfma<<<dim3(128, 4), 512, 0, stream>>>(
        xc, Bp2, h_hi[in], h_lo[in], h_hi[ob], h_lo[ob],
        cbuf, out, t, t == 0, t == NT - 1);
  }
}

// Round 5
// 214.482 us; speedup vs baseline: 1.8290x; 1.0192x over previous
//
#include <hip/hip_runtime.h>

// ConvLSTM2D: B=16,T=8,H=W=256,C=3,F=64,stride=16 -> Ho=Wo=16, 4F=256
#define NB   16
#define NT   8
#define HIN  256
#define CIN  3
#define NF   64
#define OC   256
#define HO   16
#define WOUT 16

typedef short short8 __attribute__((ext_vector_type(8)));
typedef float f32x16 __attribute__((ext_vector_type(16)));

__device__ __forceinline__ unsigned short f2bf(float x) {
  union { float f; unsigned int u; } v; v.f = x;
  unsigned int r = v.u + 0x7fffu + ((v.u >> 16) & 1u);
  return (unsigned short)(r >> 16);
}

// ---------------- Kernel 1: strided input conv, permuted-column output -------
// n = (oc&63)*4 + (oc>>6)  (filter-major, gate-minor); bias folded in.
__global__ __launch_bounds__(256) void input_conv(
    const float* __restrict__ x, const float* __restrict__ Wx,
    const float* __restrict__ bias, float* __restrict__ xc)
{
  const int ho = blockIdx.x;
  const int bt = blockIdx.y;
  const int oc = threadIdx.x;

  __shared__ float patch[3 * 16 * 12];  // k padded 9->12 for float4 reads
  for (int idx = threadIdx.x; idx < 432; idx += 256) {
    int r = idx / 144, rem = idx % 144;
    int wo = rem / 9, k = rem % 9;
    int kw = k / 3, c = k % 3;
    patch[(r * 16 + wo) * 12 + k] =
        x[(((size_t)bt * HIN + (ho * 16 + r)) * HIN + (wo * 16 + kw)) * CIN + c];
  }
  float w[27];
#pragma unroll
  for (int k = 0; k < 27; ++k) w[k] = Wx[(size_t)k * OC + oc];
  __syncthreads();

  const float bv = bias[oc];
  const int n = (oc & 63) * 4 + (oc >> 6);
  for (int wo = 0; wo < 16; ++wo) {
    float acc = bv;
#pragma unroll
    for (int kh = 0; kh < 3; ++kh) {
      const float* pp = &patch[(kh * 16 + wo) * 12];
      float4 p0 = *(const float4*)pp;
      float4 p1 = *(const float4*)(pp + 4);
      float p8 = pp[8];
      const float* wk = &w[kh * 9];
      acc = fmaf(p0.x, wk[0], fmaf(p0.y, wk[1], fmaf(p0.z, wk[2], acc)));
      acc = fmaf(p0.w, wk[3], fmaf(p1.x, wk[4], fmaf(p1.y, wk[5], acc)));
      acc = fmaf(p1.z, wk[6], fmaf(p1.w, wk[7], fmaf(p8, wk[8], acc)));
    }
    xc[(((size_t)bt * HO + ho) * WOUT + wo) * OC + n] = acc;
  }
}

// ---------------- Kernel 2: Wh -> bf16 fragment panels (coalesced transpose) -
// Bp[nb(8)][u(36: tap*4+q)][lane(64)][j(8)] bf16; n = nb*32+(lane&31),
// ci = q*16+(lane>>5)*8+j. One block per tap; Wh tap-slice staged in LDS.
__global__ __launch_bounds__(256) void conv_weights(
    const float* __restrict__ Wh, unsigned short* __restrict__ Bp)
{
  __shared__ float wt[64 * 256];  // [ci][oc], 64 KB
  const int tap = blockIdx.x;
  const int t = threadIdx.x;
#pragma unroll
  for (int i = 0; i < 16; ++i) {
    int chunk = t + i * 256;  // 4096 float4 chunks
    *(float4*)&wt[chunk * 4] = *(const float4*)&Wh[(size_t)tap * 16384 + chunk * 4];
  }
  __syncthreads();
#pragma unroll
  for (int rep = 0; rep < 8; ++rep) {
    int u = t + rep * 256;          // (nb,q,l) flat, 2048 total
    int nb = u >> 8, q = (u >> 6) & 3, l = u & 63;
    int n = nb * 32 + (l & 31);
    int oc = (n & 3) * 64 + (n >> 2);   // inverse column permutation
    int ci0 = q * 16 + (l >> 5) * 8;
    short8 v;
#pragma unroll
    for (int j = 0; j < 8; ++j) v[j] = (short)f2bf(wt[(ci0 + j) * 256 + oc]);
    *(short8*)&Bp[(size_t)((nb * 36 + tap * 4 + q) * 64 + l) * 8] = v;
  }
}

// ---------------- Kernel 3: LSTM step, LDS-staged single-pass bf16 MFMA ------
// GEMM M=4096,N=256,K=576 (9 taps x 64 ci). Grid (32 mb, 8 nb) = 256 blocks.
// Block: m-tile 128 (half image), n-tile 32; 8 waves = 4 m-frags x split-K-2.
// A: padded 10x18 halo of h[b], XOR-swizzled bf16 in LDS. B: frag-contiguous.
#define A_BYTES 23040   // 180 cells * 128 B
#define B_BYTES 36864   // 36 units * 1024 B
__global__ __launch_bounds__(512, 2) void lstm_step(
    const float* __restrict__ xc, const unsigned short* __restrict__ Bp,
    const unsigned short* __restrict__ h_in, unsigned short* __restrict__ h_out,
    float* __restrict__ c_st, float* __restrict__ out,
    int t, int first, int last)
{
  const int mb  = blockIdx.x;        // 0..31
  const int nb  = blockIdx.y;        // 0..7
  const int b   = mb >> 1;
  const int ho0 = (mb & 1) * 8;
  const int tid = threadIdx.x;
  const int w    = tid >> 6;
  const int lane = tid & 63;
  const int mf = w >> 1, kk = w & 1;

  __shared__ __align__(16) char smem[A_BYTES + B_BYTES];   // 59,904 B
  unsigned short* Bs = (unsigned short*)(smem + A_BYTES);
  float* zs = (float*)smem;          // overlay: z[2][32][129] = 33,024 B

  f32x16 acc = (f32x16)(0.0f);

  if (!first) {
    // ---- stage A: 1440 16B chunks (10x18 halo cells x 128 B, zero-padded)
    for (int j = tid; j < 1440; j += 512) {
      int cell = j >> 3, sub = j & 7;
      int r = cell / 18, c = cell - r * 18;
      int y = ho0 + r - 1, xcol = c - 1;
      float4 v = make_float4(0.f, 0.f, 0.f, 0.f);
      if ((unsigned)y < 16u && (unsigned)xcol < 16u)
        v = *(const float4*)(h_in + (((size_t)b * 256 + y * 16 + xcol) * 64 + sub * 8));
      int byte = (cell * 128 + sub * 16) ^ ((cell & 7) << 4);  // T2 swizzle
      *(float4*)(smem + byte) = v;
    }
    // ---- stage B: 2304 16B chunks, linear (frag reads are lane-contiguous)
    for (int j = tid; j < 2304; j += 512)
      *(float4*)((char*)Bs + j * 16) = *(const float4*)(Bp + (size_t)nb * 18432 + j * 8);
    __syncthreads();

    // per-lane A center cell: local pos p -> (row+1, col+1) in 10x18 pad grid
    const int p = mf * 32 + (lane & 31);
    const int cell0 = ((p >> 4) + 1) * 18 + (p & 15) + 1;
    const int cib = (lane >> 5) * 16;   // byte half-offset within 32B k-quarter

#pragma unroll
    for (int uu = 0; uu < 18; ++uu) {
      const int u = uu * 2 + kk;       // this wave's k-units
      const int tap = u >> 2, q = u & 3;
      const int dy = tap / 3 - 1, dx = tap % 3 - 1;
      const int cell = cell0 + dy * 18 + dx;
      const int abyte = (cell * 128 + q * 32 + cib) ^ ((cell & 7) << 4);
      short8 a  = *(const short8*)(smem + abyte);
      short8 bb = *(const short8*)((const char*)Bs + u * 1024 + lane * 16);
      acc = __builtin_amdgcn_mfma_f32_32x32x16_bf16(a, bb, acc, 0, 0, 0);
    }
    __syncthreads();  // A/B dead; safe to overlay z

    // dump partials: z[kk][col][pos(129 pad)]
    const int col = lane & 31;
#pragma unroll
    for (int rr = 0; rr < 4; ++rr) {
      int posl = mf * 32 + rr * 8 + (lane >> 5) * 4;
      float4 vv = make_float4(acc[rr * 4], acc[rr * 4 + 1], acc[rr * 4 + 2], acc[rr * 4 + 3]);
      *(float4*)&zs[(kk * 32 + col) * 129 + posl] = vv;
    }
  }
  __syncthreads();

  // ---- fused epilogue: 2 cells/thread (pos = tid&127, f = tid>>7 and +4)
  const int pos = tid & 127;
  const int fhalf = tid >> 7;               // 0..3
  const int gpos = ho0 * 16 + pos;
  const float* xcb = xc + ((size_t)(b * NT + t) * 256 + gpos) * 256 + nb * 32;
#pragma unroll
  for (int e = 0; e < 2; ++e) {
    int f = fhalf + e * 4;                  // 0..7 local filter
    float zq0 = 0.f, zq1 = 0.f, zq2 = 0.f, zq3 = 0.f;
    if (!first) {
      zq0 = zs[(f * 4 + 0) * 129 + pos] + zs[(32 + f * 4 + 0) * 129 + pos];
      zq1 = zs[(f * 4 + 1) * 129 + pos] + zs[(32 + f * 4 + 1) * 129 + pos];
      zq2 = zs[(f * 4 + 2) * 129 + pos] + zs[(32 + f * 4 + 2) * 129 + pos];
      zq3 = zs[(f * 4 + 3) * 129 + pos] + zs[(32 + f * 4 + 3) * 129 + pos];
    }
    float4 xq = *(const float4*)(xcb + f * 4);
    float zi = zq0 + xq.x, zf_ = zq1 + xq.y, zg = zq2 + xq.z, zo = zq3 + xq.w;
    float ig = fminf(fmaxf(fmaf(zi, 0.2f, 0.5f), 0.f), 1.f);
    float fg = fminf(fmaxf(fmaf(zf_, 0.2f, 0.5f), 0.f), 1.f);
    float og = fminf(fmaxf(fmaf(zo, 0.2f, 0.5f), 0.f), 1.f);
    size_t ci = ((size_t)b * 256 + gpos) * 64 + nb * 8 + f;
    float cold = first ? 0.f : c_st[ci];
    float cn = fmaf(fg, cold, ig * zg);
    c_st[ci] = cn;
    float h = og * cn;
    h_out[ci] = f2bf(h);
    if (last) out[ci] = h;
  }
}

extern "C" void kernel_launch(void* const* d_in, const int* in_sizes, int n_in,
                              void* d_out, int out_size, void* d_ws, size_t ws_size,
                              hipStream_t stream) {
  const float* x    = (const float*)d_in[0];
  const float* Wx   = (const float*)d_in[1];
  const float* Wh   = (const float*)d_in[2];
  const float* bias = (const float*)d_in[3];
  float* out = (float*)d_out;

  char* ws = (char*)d_ws;
  float*          xc = (float*)ws;                         // 33,554,432 B
  unsigned short* Bp = (unsigned short*)(ws + 33554432);   //    294,912 B
  unsigned short* h0 = (unsigned short*)(ws + 33849344);   //    524,288 B
  unsigned short* h1 = (unsigned short*)(ws + 34373632);   //    524,288 B
  float*          cb = (float*)(ws + 34897920);            //  1,048,576 B

  input_conv<<<dim3(HO, NB * NT), 256, 0, stream>>>(x, Wx, bias, xc);
  conv_weights<<<9, 256, 0, stream>>>(Wh, Bp);

  for (int t = 0; t < NT; ++t) {
    unsigned short* hin  = (t & 1) ? h1 : h0;   // unused at t==0
    unsigned short* hout = (t & 1) ? h0 : h1;
    lstm_step<<<dim3(32, 8), 512, 0, stream>>>(
        xc, Bp, hin, hout, cb, out, t, t == 0, t == NT - 1);
  }
}